// Round 1
// baseline (71.103 us; speedup 1.0000x reference)
//
#include <hip/hip_runtime.h>
#include <hip/hip_bf16.h>
#include <stdint.h>

// Maj3FC: out[b,c] = 2.25 * sum_g sign( sum_{k<3} sign(x[b,3g+k])*sign(w[c,3g+k]) )
// B=512, C_IN=1536, C_OUT=512, G=512 groups of 3.
//
// Encoding: per row, two bitplanes P (v>0) and N (v<0). Each group of 3
// occupies one nibble (bits 0..2; bit 3 = 0). 8 groups/word -> 64 words/row.
// Exact integer math -> absmax 0 vs reference.

#define CIN   1536
#define B_DIM 512
#define COUT  512
#define WORDS 64   // 1536 elems / (8 groups * 3 elems per word)

// ---------------- pack kernel ----------------
// grid = 256 blocks x 256 threads. Blocks 0..127 pack x (4 rows each),
// blocks 128..255 pack w (4 rows each). Coalesced float4 staging into LDS,
// then 1 thread per packed word (4 rows * 64 words = 256 threads).
__global__ __launch_bounds__(256) void pack_kernel(
    const float* __restrict__ x, const float* __restrict__ w,
    uint2* __restrict__ px, uint2* __restrict__ pw) {
  __shared__ float buf[4 * CIN];
  int bid = blockIdx.x;
  const float* src;
  uint2* dst;
  int row0;
  if (bid < 128) { src = x;  dst = px; row0 = bid * 4; }
  else           { src = w;  dst = pw; row0 = (bid - 128) * 4; }

  const float4* s4 = (const float4*)(src + (size_t)row0 * CIN);
  float4* b4 = (float4*)buf;
  #pragma unroll
  for (int i = threadIdx.x; i < 4 * CIN / 4; i += 256) b4[i] = s4[i];
  __syncthreads();

  int r  = threadIdx.x >> 6;   // 0..3 row within block
  int wd = threadIdx.x & 63;   // 0..63 word
  const float* rowp = buf + r * CIN + wd * 24;
  unsigned P = 0, N = 0;
  #pragma unroll
  for (int k = 0; k < 24; k++) {
    float v = rowp[k];
    unsigned bit = (unsigned)((k / 3) * 4 + (k % 3));
    P |= (v > 0.0f ? 1u : 0u) << bit;
    N |= (v < 0.0f ? 1u : 0u) << bit;
  }
  dst[(size_t)(row0 + r) * WORDS + wd] = make_uint2(P, N);
}

// ---------------- main kernel ----------------
// 16x16 output tile per block, 256 threads, 1 output each.
// grid = (COUT/16, B/16) = (32, 32) = 1024 blocks -> 4 blocks/CU.
// LDS: 2 * 16 * 65 * 8B = 16.6 KB (65 stride kills bank conflicts on the
// w-row reads; x-row reads are 16-lane broadcasts).
__global__ __launch_bounds__(256) void maj3_kernel(
    const uint2* __restrict__ px, const uint2* __restrict__ pw,
    float* __restrict__ out) {
  __shared__ uint2 sx[16][WORDS + 1];
  __shared__ uint2 sw[16][WORDS + 1];

  const int b0 = blockIdx.y * 16;
  const int c0 = blockIdx.x * 16;
  const int tid = threadIdx.x;

  // cooperative load: 16 rows x 64 words for each operand (1024 uint2 each)
  #pragma unroll
  for (int i = tid; i < 16 * WORDS; i += 256) {
    int r = i >> 6, wd = i & 63;
    sx[r][wd] = px[(size_t)(b0 + r) * WORDS + wd];
    sw[r][wd] = pw[(size_t)(c0 + r) * WORDS + wd];
  }
  __syncthreads();

  const int tx = tid & 15;   // c within tile
  const int ty = tid >> 4;   // b within tile

  const unsigned M1 = 0x11111111u, M8 = 0x88888888u;
  int acc_p = 0, acc_n = 0;

  #pragma unroll 8
  for (int wd = 0; wd < WORDS; wd++) {
    uint2 xa = sx[ty][wd];
    uint2 wb = sw[tx][wd];
    unsigned pos = (xa.x & wb.x) | (xa.y & wb.y);  // product == +1
    unsigned neg = (xa.x & wb.y) | (xa.y & wb.x);  // product == -1
    // per-nibble 3-bit popcounts (cp, cn in [0,3], bit3 of each nibble 0)
    unsigned cp = (pos & M1) + ((pos >> 1) & M1) + ((pos >> 2) & M1);
    unsigned cn = (neg & M1) + ((neg >> 1) & M1) + ((neg >> 2) & M1);
    // per-nibble: u nibble = cp - cn + 8  (no inter-nibble borrow: >= 5)
    unsigned u = (cp | M8) - cn;   // bit3 set  <=> cp >= cn
    unsigned t = u - M1;           // bit3 set  <=> cp >  cn   (>= 4, no borrow)
    acc_p += __popc(t & M8);       // groups with sign +1
    acc_n += __popc(~u & M8);      // groups with sign -1
  }

  out[(size_t)(b0 + ty) * COUT + (c0 + tx)] = 2.25f * (float)(acc_p - acc_n);
}

extern "C" void kernel_launch(void* const* d_in, const int* in_sizes, int n_in,
                              void* d_out, int out_size, void* d_ws, size_t ws_size,
                              hipStream_t stream) {
  const float* x = (const float*)d_in[0];   // [512, 1536]
  const float* w = (const float*)d_in[1];   // [512, 1536]
  float* out = (float*)d_out;               // [512, 512]

  uint2* px = (uint2*)d_ws;                 // [512][64]  (256 KB)
  uint2* pw = px + (size_t)B_DIM * WORDS;   // [512][64]  (256 KB)

  pack_kernel<<<256, 256, 0, stream>>>(x, w, px, pw);

  dim3 grid(COUT / 16, B_DIM / 16);
  maj3_kernel<<<grid, 256, 0, stream>>>(px, pw, out);
}